// Round 6
// baseline (332.685 us; speedup 1.0000x reference)
//
#include <hip/hip_runtime.h>
#include <hip/hip_bf16.h>
#include <stdint.h>
#include <math.h>

#define NR 16384
#define DIM 768
#define KEPS 1e-8f

#define BMT 256                      // tile edge
#define BKT 64                       // K per tile
#define NB (NR / BMT)                // 64
#define KT (DIM / BKT)               // 12
#define NTILES (NB * (NB + 1) / 2)   // 2080

typedef __attribute__((ext_vector_type(4))) float f32x4;
typedef _Float16 f16x8 __attribute__((ext_vector_type(8)));

__device__ inline uint32_t fkey(float f) {
    union { float f; uint32_t u; } v; v.f = f;
    return (v.u & 0x80000000u) ? ~v.u : (v.u | 0x80000000u);
}
__device__ inline float unkey(uint32_t k) {
    union { uint32_t u; float f; } v;
    v.u = (k & 0x80000000u) ? (k ^ 0x80000000u) : ~k;
    return v.f;
}

__device__ inline void gload16(const ushort* g, const ushort* l) {
    __builtin_amdgcn_global_load_lds(
        (const __attribute__((address_space(1))) void*)g,
        (__attribute__((address_space(3))) void*)l,
        16, 0, 0);
}

// ---------------- Kernel 1: row L2-normalize, fp32 -> fp16 -------------------
__global__ __launch_bounds__(256) void k_norm(const float* __restrict__ X,
                                              ushort* __restrict__ Xn) {
    const int wid = threadIdx.x >> 6, lane = threadIdx.x & 63;
    const int row = blockIdx.x * 4 + wid;
    const float4* xr = (const float4*)(X + (size_t)row * DIM) + lane * 3;
    float4 a = xr[0], b = xr[1], c = xr[2];
    float s = a.x*a.x + a.y*a.y + a.z*a.z + a.w*a.w
            + b.x*b.x + b.y*b.y + b.z*b.z + b.w*b.w
            + c.x*c.x + c.y*c.y + c.z*c.z + c.w*c.w;
#pragma unroll
    for (int m = 32; m >= 1; m >>= 1) s += __shfl_xor(s, m);
    const float rn = 1.0f / fmaxf(sqrtf(s), KEPS);
    float v[12] = {a.x,a.y,a.z,a.w,b.x,b.y,b.z,b.w,c.x,c.y,c.z,c.w};
    uint32_t p[6];
#pragma unroll
    for (int i = 0; i < 6; ++i) {
        union { _Float16 h[2]; uint32_t u; } pk;
        pk.h[0] = (_Float16)(v[2*i] * rn);
        pk.h[1] = (_Float16)(v[2*i+1] * rn);
        p[i] = pk.u;
    }
    uint2* dst = (uint2*)(Xn + (size_t)row * DIM + lane * 12);
    dst[0] = make_uint2(p[0], p[1]);
    dst[1] = make_uint2(p[2], p[3]);
    dst[2] = make_uint2(p[4], p[5]);
}

// ---------------- Kernel 1b: init nn-max keys --------------------------------
__global__ __launch_bounds__(256) void k_init(uint32_t* __restrict__ nnkey) {
    nnkey[blockIdx.x * 256 + threadIdx.x] = fkey(-2.0f);
}

// ------ Kernel 2: 256^2 upper-tri tile, 1024 thr, dbuf counted-vmcnt ---------
// 16 waves (4x4), wave tile 64x64 (acc 64 regs -> 4 waves/SIMD proven in R5).
// LDS: dbuf x khalf x {A,B} [256][32] f16 regions = 128 KiB, 1 block/CU.
// Schedule per kt: STAGE(kt+1) -> vmcnt(4) -> barrier -> ds_read+MFMA ->
// barrier. vmcnt(4) retires exactly STAGE(kt) (4 issues/thread/kt); the
// prefetch has a full kt of MFMA cover and never drains. Last kt peeled
// with vmcnt(0). Swizzle = R4's measured-zero-conflict (r>>1)&3 form.
__global__ __launch_bounds__(1024, 4) void k_maxdot(const ushort* __restrict__ Xn,
                                                    uint32_t* __restrict__ nnkey) {
    __shared__ ushort sA[2][2][256 * 32];
    __shared__ ushort sB[2][2][256 * 32];
    const int tid  = threadIdx.x;
    const int lane = tid & 63, wid = tid >> 6;
    const int l15 = lane & 15, lhi = (lane >> 4) & 3;
    const int wr = wid >> 2, wc = wid & 3;       // 4x4 wave grid

    // XCD-chunked bijective swizzle (NTILES % 8 == 0)
    int t = (int)blockIdx.x;
    t = (t & 7) * (NTILES / 8) + (t >> 3);
    // decode upper-triangle tile id -> (rb, cb), cb >= rb; S(rb)=rb*(129-rb)/2
    int rb = (int)((129.0f - sqrtf(16641.0f - 8.0f * (float)t)) * 0.5f);
    if (rb < 0) rb = 0;
    if (rb > NB - 1) rb = NB - 1;
    while (rb > 0 && rb * (129 - rb) / 2 > t) --rb;
    while ((rb + 1) * (129 - (rb + 1)) / 2 <= t) ++rb;
    const int cb = rb + (t - rb * (129 - rb) / 2);
    const int rowbase = rb * BMT;
    const int colbase = cb * BMT;

    f32x4 acc[4][4];
    const f32x4 z = {0.f, 0.f, 0.f, 0.f};
#pragma unroll
    for (int i = 0; i < 4; ++i)
#pragma unroll
        for (int j = 0; j < 4; ++j) acc[i][j] = z;

    // stage kt into buf: 4 regions (A/B x kh0/kh1), 1 gload16 per thread each
    const int sR = tid >> 2;                       // region row 0..255
    const int sC = (tid & 3) ^ ((sR >> 1) & 3);    // swizzled 16B chunk
    auto STAGE = [&](int buf, int kt) {
        const size_t kbase = (size_t)kt * BKT;
        const ushort* gA0 = Xn + (size_t)(rowbase + sR) * DIM + kbase + sC * 8;
        const ushort* gA1 = gA0 + 32;
        const ushort* gB0 = Xn + (size_t)(colbase + sR) * DIM + kbase + sC * 8;
        const ushort* gB1 = gB0 + 32;
        gload16(gA0, &sA[buf][0][wid * 512]);
        gload16(gA1, &sA[buf][1][wid * 512]);
        gload16(gB0, &sB[buf][0][wid * 512]);
        gload16(gB1, &sB[buf][1][wid * 512]);
    };
    // swizzled fragment read: row r, k-chunk lhi within a [256][32] region
    auto RD = [&](const ushort* region, int r) -> f16x8 {
        return *(const f16x8*)(region + r * 32 + ((lhi ^ ((r >> 1) & 3)) << 3));
    };
    auto COMPUTE = [&](int b) {
#pragma unroll
        for (int ks = 0; ks < 2; ++ks) {
            f16x8 af[4], bg[4];
#pragma unroll
            for (int mf = 0; mf < 4; ++mf) af[mf] = RD(sA[b][ks], wr * 64 + mf * 16 + l15);
#pragma unroll
            for (int nf = 0; nf < 4; ++nf) bg[nf] = RD(sB[b][ks], wc * 64 + nf * 16 + l15);
#pragma unroll
            for (int mf = 0; mf < 4; ++mf)
#pragma unroll
                for (int nf = 0; nf < 4; ++nf)
                    acc[mf][nf] = __builtin_amdgcn_mfma_f32_16x16x32_f16(
                        af[mf], bg[nf], acc[mf][nf], 0, 0, 0);
        }
    };

    STAGE(0, 0);
    for (int kt = 0; kt < KT - 1; ++kt) {
        STAGE((kt + 1) & 1, kt + 1);                     // prefetch next
        asm volatile("s_waitcnt vmcnt(4)" ::: "memory"); // kt's 4 loads landed
        __builtin_amdgcn_s_barrier();
        __builtin_amdgcn_sched_barrier(0);
        COMPUTE(kt & 1);
        __builtin_amdgcn_s_barrier();                    // reads done before overwrite
        __builtin_amdgcn_sched_barrier(0);
    }
    // peeled last kt
    asm volatile("s_waitcnt vmcnt(0)" ::: "memory");
    __builtin_amdgcn_s_barrier();
    __builtin_amdgcn_sched_barrier(0);
    COMPUTE((KT - 1) & 1);

    // ---- diagonal tiles: mask self-similarity to -1 ----
    if (rb == cb) {
#pragma unroll
        for (int mf = 0; mf < 4; ++mf)
#pragma unroll
            for (int nf = 0; nf < 4; ++nf)
#pragma unroll
                for (int rr = 0; rr < 4; ++rr) {
                    const int rl = wr * 64 + mf * 16 + lhi * 4 + rr;
                    const int cl = wc * 64 + nf * 16 + l15;
                    if (rl == cl) acc[mf][nf][rr] = -1.0f;
                }
    }

    // ---- row-max: over nf regs, then 16 cols (lane bits 0..3) ----
#pragma unroll
    for (int mf = 0; mf < 4; ++mf)
#pragma unroll
        for (int rr = 0; rr < 4; ++rr) {
            float v = fmaxf(fmaxf(acc[mf][0][rr], acc[mf][1][rr]),
                            fmaxf(acc[mf][2][rr], acc[mf][3][rr]));
            v = fmaxf(v, __shfl_xor(v, 1));
            v = fmaxf(v, __shfl_xor(v, 2));
            v = fmaxf(v, __shfl_xor(v, 4));
            v = fmaxf(v, __shfl_xor(v, 8));
            if (l15 == 0) {
                const int r = rowbase + wr * 64 + mf * 16 + lhi * 4 + rr;
                atomicMax(&nnkey[r], fkey(v));
            }
        }

    // ---- col-max: over mf,rr regs, then 4 row-groups (lane bits 4,5) ----
#pragma unroll
    for (int nf = 0; nf < 4; ++nf) {
        float v = -2.0f;
#pragma unroll
        for (int mf = 0; mf < 4; ++mf)
#pragma unroll
            for (int rr = 0; rr < 4; ++rr) v = fmaxf(v, acc[mf][nf][rr]);
        v = fmaxf(v, __shfl_xor(v, 16));
        v = fmaxf(v, __shfl_xor(v, 32));
        if ((lane >> 4) == 0) {
            const int c = colbase + wc * 64 + nf * 16 + l15;
            atomicMax(&nnkey[c], fkey(v));
        }
    }
}

// ---------------- Kernel 3: compute loss from nn-max keys --------------------
__global__ __launch_bounds__(256) void k_loss(const uint32_t* __restrict__ nnkey,
                                              float* __restrict__ out) {
    float local = 0.0f;
    for (int r = threadIdx.x; r < NR; r += 256) {
        const float m = unkey(nnkey[r]);
        const float d = sqrtf(fmaxf(2.0f - 2.0f * m, 0.0f));
        local += logf(d + KEPS);
    }
#pragma unroll
    for (int m = 32; m >= 1; m >>= 1) local += __shfl_xor(local, m);
    __shared__ float red[4];
    const int lane = threadIdx.x & 63, wid = threadIdx.x >> 6;
    if (lane == 0) red[wid] = local;
    __syncthreads();
    if (threadIdx.x == 0)
        out[0] = -(red[0] + red[1] + red[2] + red[3]) / (float)NR;
}

extern "C" void kernel_launch(void* const* d_in, const int* in_sizes, int n_in,
                              void* d_out, int out_size, void* d_ws, size_t ws_size,
                              hipStream_t stream) {
    const float* X = (const float*)d_in[0];
    float* out = (float*)d_out;
    ushort* Xn = (ushort*)d_ws;                                        // 24 MiB fp16
    uint32_t* nnkey = (uint32_t*)((char*)d_ws + (size_t)NR * DIM * 2); // 64 KiB

    k_norm<<<NR / 4, 256, 0, stream>>>(X, Xn);
    k_init<<<NR / 256, 256, 0, stream>>>(nnkey);
    k_maxdot<<<NTILES, 1024, 0, stream>>>(Xn, nnkey);
    k_loss<<<1, 256, 0, stream>>>(nnkey, out);
}